// Round 1
// baseline (522.086 us; speedup 1.0000x reference)
//
#include <hip/hip_runtime.h>

#define B_  8
#define N_  8192
#define S_  2048
#define C1_ 128
#define C2_ 256
#define H0_ 256
#define H1_ 128
#define R_  (B_ * N_)   // 65536

// ---------------- zero stats ----------------
__global__ void zero_kernel(float* __restrict__ p, int n) {
    int i = blockIdx.x * 256 + threadIdx.x;
    if (i < n) p[i] = 0.f;
}

// ---------------- top-3 nearest neighbors ----------------
// grid: B_ * (N_/256) = 256 blocks, 256 threads. Stage xyz2[b] in LDS.
__global__ __launch_bounds__(256) void top3_kernel(
    const float* __restrict__ xyz1, const float* __restrict__ xyz2,
    int* __restrict__ out_idx, float* __restrict__ out_w)
{
    __shared__ float sx[S_], sy[S_], sz[S_];
    int b = blockIdx.x >> 5;       // 32 n-tiles per batch
    int ntile = blockIdx.x & 31;
    const float* src = xyz2 + (size_t)b * S_ * 3;
    for (int i = threadIdx.x; i < S_; i += 256) {
        sx[i] = src[i * 3 + 0];
        sy[i] = src[i * 3 + 1];
        sz[i] = src[i * 3 + 2];
    }
    __syncthreads();

    int n = ntile * 256 + threadIdx.x;
    size_t row = (size_t)b * N_ + n;
    float px = xyz1[row * 3 + 0], py = xyz1[row * 3 + 1], pz = xyz1[row * 3 + 2];

    float d0 = 1e30f, d1 = 1e30f, d2 = 1e30f;
    int i0 = 0, i1 = 0, i2 = 0;
    #pragma unroll 4
    for (int s = 0; s < S_; ++s) {
        float dx = px - sx[s], dy = py - sy[s], dz = pz - sz[s];
        float d = dx * dx + dy * dy + dz * dz;
        if (d < d2) {
            if (d < d1) {
                d2 = d1; i2 = i1;
                if (d < d0) { d1 = d0; i1 = i0; d0 = d; i0 = s; }
                else        { d1 = d;  i1 = s; }
            } else { d2 = d; i2 = s; }
        }
    }
    float r0 = 1.f / (d0 + 1e-8f), r1 = 1.f / (d1 + 1e-8f), r2 = 1.f / (d2 + 1e-8f);
    float inv = 1.f / (r0 + r1 + r2);
    out_idx[row * 3 + 0] = i0; out_idx[row * 3 + 1] = i1; out_idx[row * 3 + 2] = i2;
    out_w[row * 3 + 0] = r0 * inv; out_w[row * 3 + 1] = r1 * inv; out_w[row * 3 + 2] = r2 * inv;
}

// ---------------- gather + weighted interp ----------------
// 4 rows per block (64 lanes each, float4 over C2=256 channels). grid = R_/4.
__global__ __launch_bounds__(256) void interp_kernel(
    const float* __restrict__ points2, const int* __restrict__ idx3,
    const float* __restrict__ w3, float* __restrict__ interp)
{
    int t = threadIdx.x;
    size_t row = (size_t)blockIdx.x * 4 + (t >> 6);
    int lane = t & 63;
    int b = (int)(row >> 13);   // row / N_
    const float* p2 = points2 + (size_t)b * S_ * C2_;
    int ia = idx3[row * 3 + 0], ib = idx3[row * 3 + 1], ic = idx3[row * 3 + 2];
    float wa = w3[row * 3 + 0], wb = w3[row * 3 + 1], wc = w3[row * 3 + 2];
    float4 va = *(const float4*)(p2 + (size_t)ia * C2_ + lane * 4);
    float4 vb = *(const float4*)(p2 + (size_t)ib * C2_ + lane * 4);
    float4 vc = *(const float4*)(p2 + (size_t)ic * C2_ + lane * 4);
    float4 o;
    o.x = wa * va.x + wb * vb.x + wc * vc.x;
    o.y = wa * va.y + wb * vb.y + wc * vc.y;
    o.z = wa * va.z + wb * vb.z + wc * vc.z;
    o.w = wa * va.w + wb * vb.w + wc * vc.w;
    *(float4*)(interp + row * C2_ + lane * 4) = o;
}

// ---------------- tiled f32 GEMM: C[r][o] = sum_k A[r][k] * W[o][k] + bias[o] ----------------
// MODE 0: A = concat(points1[r][0:128], interp[r][0:256]); MODE 1: A = relu(bn(hpre)) applied at load.
// BM=128, BN=128, BK=16, 256 threads, 8x8 per thread.
template<int MODE, int K, int O>
__global__ __launch_bounds__(256) void gemm_kernel(
    const float* __restrict__ A0, const float* __restrict__ A1,
    const float* __restrict__ W, const float* __restrict__ bias,
    const float* __restrict__ scale, const float* __restrict__ shift,
    float* __restrict__ Cout)
{
    constexpr int BM = 128, BN = 128, BK = 16;
    __shared__ float As[BK][BM + 4];
    __shared__ float Ws[BK][BN + 4];
    int r0 = blockIdx.x * BM;
    int o0 = blockIdx.y * BN;
    int tid = threadIdx.x;
    int tx = tid & 15, ty = tid >> 4;

    float acc[8][8] = {};

    for (int k0 = 0; k0 < K; k0 += BK) {
        #pragma unroll
        for (int i = 0; i < 8; ++i) {
            int e = i * 256 + tid;
            int m = e >> 4, kk = e & 15;
            int r = r0 + m, k = k0 + kk;
            float a;
            if (MODE == 0) {
                a = (k < C1_) ? A0[(size_t)r * C1_ + k]
                              : A1[(size_t)r * C2_ + (k - C1_)];
            } else {
                a = A0[(size_t)r * K + k];
                a = fmaxf(0.f, a * scale[k] + shift[k]);
            }
            As[kk][m] = a;
        }
        #pragma unroll
        for (int i = 0; i < 8; ++i) {
            int e = i * 256 + tid;
            int m = e >> 4, kk = e & 15;
            Ws[kk][m] = W[(size_t)(o0 + m) * K + (k0 + kk)];
        }
        __syncthreads();

        #pragma unroll
        for (int kk = 0; kk < BK; ++kk) {
            float av[8], bv[8];
            *(float4*)&av[0] = *(const float4*)&As[kk][ty * 8];
            *(float4*)&av[4] = *(const float4*)&As[kk][ty * 8 + 4];
            *(float4*)&bv[0] = *(const float4*)&Ws[kk][tx * 8];
            *(float4*)&bv[4] = *(const float4*)&Ws[kk][tx * 8 + 4];
            #pragma unroll
            for (int i = 0; i < 8; ++i)
                #pragma unroll
                for (int j = 0; j < 8; ++j)
                    acc[i][j] += av[i] * bv[j];
        }
        __syncthreads();
    }

    float bj[8];
    #pragma unroll
    for (int j = 0; j < 8; ++j) bj[j] = bias[o0 + tx * 8 + j];
    #pragma unroll
    for (int i = 0; i < 8; ++i) {
        size_t r = r0 + ty * 8 + i;
        float4 v0, v1;
        v0.x = acc[i][0] + bj[0]; v0.y = acc[i][1] + bj[1];
        v0.z = acc[i][2] + bj[2]; v0.w = acc[i][3] + bj[3];
        v1.x = acc[i][4] + bj[4]; v1.y = acc[i][5] + bj[5];
        v1.z = acc[i][6] + bj[6]; v1.w = acc[i][7] + bj[7];
        *(float4*)(Cout + r * O + o0 + tx * 8)     = v0;
        *(float4*)(Cout + r * O + o0 + tx * 8 + 4) = v1;
    }
}

// ---------------- per-channel sums for BN stats ----------------
// block = C threads, each block handles 512 rows; coalesced column walk + 2 atomics/thread.
__global__ void stats_kernel(const float* __restrict__ X, int C,
                             float* __restrict__ sums, float* __restrict__ sumsq)
{
    int c = threadIdx.x;
    size_t r0 = (size_t)blockIdx.x * 512;
    const float* p = X + r0 * C + c;
    float s = 0.f, q = 0.f;
    for (int i = 0; i < 512; ++i) {
        float v = p[(size_t)i * C];
        s += v; q += v * v;
    }
    atomicAdd(&sums[c], s);
    atomicAdd(&sumsq[c], q);
}

__global__ void finalize_kernel(const float* __restrict__ sums, const float* __restrict__ sumsq,
                                const float* __restrict__ g, const float* __restrict__ be,
                                float* __restrict__ scale, float* __restrict__ shift, float invR)
{
    int c = threadIdx.x;
    float mean = sums[c] * invR;
    float var = sumsq[c] * invR - mean * mean;
    float s = g[c] * rsqrtf(var + 1e-5f);
    scale[c] = s;
    shift[c] = be[c] - mean * s;
}

// ---------------- final in-place BN+ReLU on d_out ----------------
__global__ __launch_bounds__(256) void bnrelu_kernel(float* __restrict__ X,
                                                     const float* __restrict__ scale,
                                                     const float* __restrict__ shift)
{
    size_t i = (size_t)blockIdx.x * 256 + threadIdx.x;   // float4 index
    float4 v = *(float4*)(X + i * 4);
    int c = (int)((i * 4) & (H1_ - 1));
    v.x = fmaxf(0.f, v.x * scale[c + 0] + shift[c + 0]);
    v.y = fmaxf(0.f, v.y * scale[c + 1] + shift[c + 1]);
    v.z = fmaxf(0.f, v.z * scale[c + 2] + shift[c + 2]);
    v.w = fmaxf(0.f, v.w * scale[c + 3] + shift[c + 3]);
    *(float4*)(X + i * 4) = v;
}

extern "C" void kernel_launch(void* const* d_in, const int* in_sizes, int n_in,
                              void* d_out, int out_size, void* d_ws, size_t ws_size,
                              hipStream_t stream)
{
    const float* xyz1    = (const float*)d_in[0];
    const float* xyz2    = (const float*)d_in[1];
    const float* points1 = (const float*)d_in[2];
    const float* points2 = (const float*)d_in[3];
    const float* w0  = (const float*)d_in[4];
    const float* b0  = (const float*)d_in[5];
    const float* g0  = (const float*)d_in[6];
    const float* be0 = (const float*)d_in[7];
    const float* w1  = (const float*)d_in[8];
    const float* b1  = (const float*)d_in[9];
    const float* g1  = (const float*)d_in[10];
    const float* be1 = (const float*)d_in[11];
    float* out = (float*)d_out;
    float* ws  = (float*)d_ws;

    float* interp = ws;                          // 65536*256 f32
    float* hpre   = ws + 16777216;               // 65536*256 f32
    int*   idx3   = (int*)(ws + 33554432);       // 65536*3 int
    float* w3     = ws + 33751040;               // 65536*3 f32
    float* stats  = ws + 33947648;               // 1536 f32
    float* sums0 = stats, *sumsq0 = stats + 256;
    float* sums1 = stats + 512, *sumsq1 = stats + 640;
    float* scale0 = stats + 768,  *shift0 = stats + 1024;
    float* scale1 = stats + 1280, *shift1 = stats + 1408;

    zero_kernel<<<3, 256, 0, stream>>>(stats, 768);
    top3_kernel<<<B_ * (N_ / 256), 256, 0, stream>>>(xyz1, xyz2, idx3, w3);
    interp_kernel<<<R_ / 4, 256, 0, stream>>>(points2, idx3, w3, interp);
    gemm_kernel<0, 384, 256><<<dim3(R_ / 128, 2), 256, 0, stream>>>(
        points1, interp, w0, b0, nullptr, nullptr, hpre);
    stats_kernel<<<128, 256, 0, stream>>>(hpre, 256, sums0, sumsq0);
    finalize_kernel<<<1, 256, 0, stream>>>(sums0, sumsq0, g0, be0, scale0, shift0, 1.f / R_);
    gemm_kernel<1, 256, 128><<<dim3(R_ / 128, 1), 256, 0, stream>>>(
        hpre, nullptr, w1, b1, scale0, shift0, out);
    stats_kernel<<<128, 128, 0, stream>>>(out, 128, sums1, sumsq1);
    finalize_kernel<<<1, 128, 0, stream>>>(sums1, sumsq1, g1, be1, scale1, shift1, 1.f / R_);
    bnrelu_kernel<<<R_ * H1_ / 4 / 256, 256, 0, stream>>>(out, scale1, shift1);
}

// Round 2
// 415.911 us; speedup vs baseline: 1.2553x; 1.2553x over previous
//
#include <hip/hip_runtime.h>

#define B_  8
#define N_  8192
#define S_  2048
#define C1_ 128
#define C2_ 256
#define H0_ 256
#define H1_ 128
#define R_  (B_ * N_)   // 65536

// ---------------- zero stats ----------------
__global__ void zero_kernel(float* __restrict__ p, int n) {
    int i = blockIdx.x * 256 + threadIdx.x;
    if (i < n) p[i] = 0.f;
}

// ---------------- top-3 nearest neighbors (split-4 per query) ----------------
// grid: B_ * (N_/64) = 1024 blocks, 256 threads = 64 queries x 4 S-splits.
// Each thread scans 512 candidates into an exact local top-3; split results are
// merged in ascending-index order with strict < (stable, matches top_k ties).
__global__ __launch_bounds__(256) void top3_kernel(
    const float* __restrict__ xyz1, const float* __restrict__ xyz2,
    int* __restrict__ out_idx, float* __restrict__ out_w)
{
    __shared__ float sx[S_], sy[S_], sz[S_];
    __shared__ float md[64][4][3];
    __shared__ int   mi[64][4][3];

    int b = blockIdx.x >> 7;        // 128 n-tiles per batch
    int ntile = blockIdx.x & 127;
    const float* src = xyz2 + (size_t)b * S_ * 3;
    for (int i = threadIdx.x; i < S_; i += 256) {
        sx[i] = src[i * 3 + 0];
        sy[i] = src[i * 3 + 1];
        sz[i] = src[i * 3 + 2];
    }
    __syncthreads();

    int q  = threadIdx.x >> 2;      // query within tile [0,64)
    int sp = threadIdx.x & 3;       // S-split [0,4)
    int n = ntile * 64 + q;
    size_t row = (size_t)b * N_ + n;
    float px = xyz1[row * 3 + 0], py = xyz1[row * 3 + 1], pz = xyz1[row * 3 + 2];

    float d0 = 1e30f, d1 = 1e30f, d2 = 1e30f;
    int i0 = 0, i1 = 0, i2 = 0;
    int sbeg = sp * (S_ / 4);
    #pragma unroll 8
    for (int s = sbeg; s < sbeg + S_ / 4; ++s) {
        float dx = px - sx[s], dy = py - sy[s], dz = pz - sz[s];
        float d = dx * dx + dy * dy + dz * dz;
        if (d < d2) {
            if (d < d1) {
                d2 = d1; i2 = i1;
                if (d < d0) { d1 = d0; i1 = i0; d0 = d; i0 = s; }
                else        { d1 = d;  i1 = s; }
            } else { d2 = d; i2 = s; }
        }
    }
    md[q][sp][0] = d0; md[q][sp][1] = d1; md[q][sp][2] = d2;
    mi[q][sp][0] = i0; mi[q][sp][1] = i1; mi[q][sp][2] = i2;
    __syncthreads();

    if (sp == 0) {
        #pragma unroll
        for (int p = 1; p < 4; ++p) {
            #pragma unroll
            for (int j = 0; j < 3; ++j) {
                float d = md[q][p][j]; int s = mi[q][p][j];
                if (d < d2) {
                    if (d < d1) {
                        d2 = d1; i2 = i1;
                        if (d < d0) { d1 = d0; i1 = i0; d0 = d; i0 = s; }
                        else        { d1 = d;  i1 = s; }
                    } else { d2 = d; i2 = s; }
                }
            }
        }
        float r0 = 1.f / (d0 + 1e-8f), r1 = 1.f / (d1 + 1e-8f), r2 = 1.f / (d2 + 1e-8f);
        float inv = 1.f / (r0 + r1 + r2);
        out_idx[row * 3 + 0] = i0; out_idx[row * 3 + 1] = i1; out_idx[row * 3 + 2] = i2;
        out_w[row * 3 + 0] = r0 * inv; out_w[row * 3 + 1] = r1 * inv; out_w[row * 3 + 2] = r2 * inv;
    }
}

// ---------------- gather + weighted interp ----------------
// 4 rows per block (64 lanes each, float4 over C2=256 channels). grid = R_/4.
__global__ __launch_bounds__(256) void interp_kernel(
    const float* __restrict__ points2, const int* __restrict__ idx3,
    const float* __restrict__ w3, float* __restrict__ interp)
{
    int t = threadIdx.x;
    size_t row = (size_t)blockIdx.x * 4 + (t >> 6);
    int lane = t & 63;
    int b = (int)(row >> 13);   // row / N_
    const float* p2 = points2 + (size_t)b * S_ * C2_;
    int ia = idx3[row * 3 + 0], ib = idx3[row * 3 + 1], ic = idx3[row * 3 + 2];
    float wa = w3[row * 3 + 0], wb = w3[row * 3 + 1], wc = w3[row * 3 + 2];
    float4 va = *(const float4*)(p2 + (size_t)ia * C2_ + lane * 4);
    float4 vb = *(const float4*)(p2 + (size_t)ib * C2_ + lane * 4);
    float4 vc = *(const float4*)(p2 + (size_t)ic * C2_ + lane * 4);
    float4 o;
    o.x = wa * va.x + wb * vb.x + wc * vc.x;
    o.y = wa * va.y + wb * vb.y + wc * vc.y;
    o.z = wa * va.z + wb * vb.z + wc * vc.z;
    o.w = wa * va.w + wb * vb.w + wc * vc.w;
    *(float4*)(interp + row * C2_ + lane * 4) = o;
}

// ---------------- tiled f32 GEMM: C[r][o] = sum_k A[r][k] * W[o][k] + bias[o] ----------------
// MODE 0: A = concat(points1[r][0:128], interp[r][0:256]); MODE 1: A = relu(bn(hpre)) applied at load.
// BM=128, BN=128, BK=16, 256 threads, 8x8 per thread.
template<int MODE, int K, int O>
__global__ __launch_bounds__(256) void gemm_kernel(
    const float* __restrict__ A0, const float* __restrict__ A1,
    const float* __restrict__ W, const float* __restrict__ bias,
    const float* __restrict__ scale, const float* __restrict__ shift,
    float* __restrict__ Cout)
{
    constexpr int BM = 128, BN = 128, BK = 16;
    __shared__ float As[BK][BM + 4];
    __shared__ float Ws[BK][BN + 4];
    int r0 = blockIdx.x * BM;
    int o0 = blockIdx.y * BN;
    int tid = threadIdx.x;
    int tx = tid & 15, ty = tid >> 4;

    float acc[8][8] = {};

    for (int k0 = 0; k0 < K; k0 += BK) {
        #pragma unroll
        for (int i = 0; i < 8; ++i) {
            int e = i * 256 + tid;
            int m = e >> 4, kk = e & 15;
            int r = r0 + m, k = k0 + kk;
            float a;
            if (MODE == 0) {
                a = (k < C1_) ? A0[(size_t)r * C1_ + k]
                              : A1[(size_t)r * C2_ + (k - C1_)];
            } else {
                a = A0[(size_t)r * K + k];
                a = fmaxf(0.f, a * scale[k] + shift[k]);
            }
            As[kk][m] = a;
        }
        #pragma unroll
        for (int i = 0; i < 8; ++i) {
            int e = i * 256 + tid;
            int m = e >> 4, kk = e & 15;
            Ws[kk][m] = W[(size_t)(o0 + m) * K + (k0 + kk)];
        }
        __syncthreads();

        #pragma unroll
        for (int kk = 0; kk < BK; ++kk) {
            float av[8], bv[8];
            *(float4*)&av[0] = *(const float4*)&As[kk][ty * 8];
            *(float4*)&av[4] = *(const float4*)&As[kk][ty * 8 + 4];
            *(float4*)&bv[0] = *(const float4*)&Ws[kk][tx * 8];
            *(float4*)&bv[4] = *(const float4*)&Ws[kk][tx * 8 + 4];
            #pragma unroll
            for (int i = 0; i < 8; ++i)
                #pragma unroll
                for (int j = 0; j < 8; ++j)
                    acc[i][j] += av[i] * bv[j];
        }
        __syncthreads();
    }

    float bj[8];
    #pragma unroll
    for (int j = 0; j < 8; ++j) bj[j] = bias[o0 + tx * 8 + j];
    #pragma unroll
    for (int i = 0; i < 8; ++i) {
        size_t r = r0 + ty * 8 + i;
        float4 v0, v1;
        v0.x = acc[i][0] + bj[0]; v0.y = acc[i][1] + bj[1];
        v0.z = acc[i][2] + bj[2]; v0.w = acc[i][3] + bj[3];
        v1.x = acc[i][4] + bj[4]; v1.y = acc[i][5] + bj[5];
        v1.z = acc[i][6] + bj[6]; v1.w = acc[i][7] + bj[7];
        *(float4*)(Cout + r * O + o0 + tx * 8)     = v0;
        *(float4*)(Cout + r * O + o0 + tx * 8 + 4) = v1;
    }
}

// ---------------- per-channel sums for BN stats ----------------
__global__ void stats_kernel(const float* __restrict__ X, int C,
                             float* __restrict__ sums, float* __restrict__ sumsq)
{
    int c = threadIdx.x;
    size_t r0 = (size_t)blockIdx.x * 512;
    const float* p = X + r0 * C + c;
    float s = 0.f, q = 0.f;
    for (int i = 0; i < 512; ++i) {
        float v = p[(size_t)i * C];
        s += v; q += v * v;
    }
    atomicAdd(&sums[c], s);
    atomicAdd(&sumsq[c], q);
}

__global__ void finalize_kernel(const float* __restrict__ sums, const float* __restrict__ sumsq,
                                const float* __restrict__ g, const float* __restrict__ be,
                                float* __restrict__ scale, float* __restrict__ shift, float invR)
{
    int c = threadIdx.x;
    float mean = sums[c] * invR;
    float var = sumsq[c] * invR - mean * mean;
    float s = g[c] * rsqrtf(var + 1e-5f);
    scale[c] = s;
    shift[c] = be[c] - mean * s;
}

// ---------------- final in-place BN+ReLU on d_out ----------------
__global__ __launch_bounds__(256) void bnrelu_kernel(float* __restrict__ X,
                                                     const float* __restrict__ scale,
                                                     const float* __restrict__ shift)
{
    size_t i = (size_t)blockIdx.x * 256 + threadIdx.x;   // float4 index
    float4 v = *(float4*)(X + i * 4);
    int c = (int)((i * 4) & (H1_ - 1));
    v.x = fmaxf(0.f, v.x * scale[c + 0] + shift[c + 0]);
    v.y = fmaxf(0.f, v.y * scale[c + 1] + shift[c + 1]);
    v.z = fmaxf(0.f, v.z * scale[c + 2] + shift[c + 2]);
    v.w = fmaxf(0.f, v.w * scale[c + 3] + shift[c + 3]);
    *(float4*)(X + i * 4) = v;
}

extern "C" void kernel_launch(void* const* d_in, const int* in_sizes, int n_in,
                              void* d_out, int out_size, void* d_ws, size_t ws_size,
                              hipStream_t stream)
{
    const float* xyz1    = (const float*)d_in[0];
    const float* xyz2    = (const float*)d_in[1];
    const float* points1 = (const float*)d_in[2];
    const float* points2 = (const float*)d_in[3];
    const float* w0  = (const float*)d_in[4];
    const float* b0  = (const float*)d_in[5];
    const float* g0  = (const float*)d_in[6];
    const float* be0 = (const float*)d_in[7];
    const float* w1  = (const float*)d_in[8];
    const float* b1  = (const float*)d_in[9];
    const float* g1  = (const float*)d_in[10];
    const float* be1 = (const float*)d_in[11];
    float* out = (float*)d_out;
    float* ws  = (float*)d_ws;

    float* interp = ws;                          // 65536*256 f32
    float* hpre   = ws + 16777216;               // 65536*256 f32
    int*   idx3   = (int*)(ws + 33554432);       // 65536*3 int
    float* w3     = ws + 33751040;               // 65536*3 f32
    float* stats  = ws + 33947648;               // 1536 f32
    float* sums0 = stats, *sumsq0 = stats + 256;
    float* sums1 = stats + 512, *sumsq1 = stats + 640;
    float* scale0 = stats + 768,  *shift0 = stats + 1024;
    float* scale1 = stats + 1280, *shift1 = stats + 1408;

    zero_kernel<<<3, 256, 0, stream>>>(stats, 768);
    top3_kernel<<<B_ * (N_ / 64), 256, 0, stream>>>(xyz1, xyz2, idx3, w3);
    interp_kernel<<<R_ / 4, 256, 0, stream>>>(points2, idx3, w3, interp);
    gemm_kernel<0, 384, 256><<<dim3(R_ / 128, 2), 256, 0, stream>>>(
        points1, interp, w0, b0, nullptr, nullptr, hpre);
    stats_kernel<<<128, 256, 0, stream>>>(hpre, 256, sums0, sumsq0);
    finalize_kernel<<<1, 256, 0, stream>>>(sums0, sumsq0, g0, be0, scale0, shift0, 1.f / R_);
    gemm_kernel<1, 256, 128><<<dim3(R_ / 128, 1), 256, 0, stream>>>(
        hpre, nullptr, w1, b1, scale0, shift0, out);
    stats_kernel<<<128, 128, 0, stream>>>(out, 128, sums1, sumsq1);
    finalize_kernel<<<1, 128, 0, stream>>>(sums1, sumsq1, g1, be1, scale1, shift1, 1.f / R_);
    bnrelu_kernel<<<R_ * H1_ / 4 / 256, 256, 0, stream>>>(out, scale1, shift1);
}

// Round 3
// 224.508 us; speedup vs baseline: 2.3255x; 1.8525x over previous
//
#include <hip/hip_runtime.h>

#define B_  8
#define N_  8192
#define S_  2048
#define C1_ 128
#define C2_ 256
#define KA_ 384   // C1_+C2_
#define H0_ 256
#define H1_ 128
#define R_  (B_ * N_)   // 65536

typedef __bf16 bf16;
typedef __attribute__((ext_vector_type(4))) __bf16 bf16x4;
typedef __attribute__((ext_vector_type(8))) __bf16 bf16x8;
typedef __attribute__((ext_vector_type(4))) float f32x4;

__device__ __forceinline__ void gload_lds16(const void* g, void* l) {
    __builtin_amdgcn_global_load_lds(
        (const __attribute__((address_space(1))) void*)g,
        (__attribute__((address_space(3))) void*)l, 16, 0, 0);
}

// ---------------- zero stats ----------------
__global__ void zero_kernel(float* __restrict__ p, int n) {
    int i = blockIdx.x * 256 + threadIdx.x;
    if (i < n) p[i] = 0.f;
}

// ---------------- f32 -> bf16 contiguous cast (weights) ----------------
__global__ __launch_bounds__(256) void cvt_kernel(const float* __restrict__ src,
                                                  bf16* __restrict__ dst, int n4) {
    int i = blockIdx.x * 256 + threadIdx.x;
    if (i < n4) {
        float4 v = *(const float4*)(src + (size_t)i * 4);
        bf16x4 o = { (bf16)v.x, (bf16)v.y, (bf16)v.z, (bf16)v.w };
        *(bf16x4*)(dst + (size_t)i * 4) = o;
    }
}

// ---------------- points1 f32 -> Abf cols [0,128) ----------------
__global__ __launch_bounds__(256) void p1cvt_kernel(const float* __restrict__ p1,
                                                    bf16* __restrict__ Abf) {
    int e = blockIdx.x * 256 + threadIdx.x;   // 4-elem chunk, 65536*32 chunks
    int row = e >> 5, kc = e & 31;
    float4 v = *(const float4*)(p1 + (size_t)row * C1_ + kc * 4);
    bf16x4 o = { (bf16)v.x, (bf16)v.y, (bf16)v.z, (bf16)v.w };
    *(bf16x4*)(Abf + (size_t)row * KA_ + kc * 4) = o;
}

// ---------------- top-3 nearest neighbors (split-4 per query) ----------------
__global__ __launch_bounds__(256) void top3_kernel(
    const float* __restrict__ xyz1, const float* __restrict__ xyz2,
    int* __restrict__ out_idx, float* __restrict__ out_w)
{
    __shared__ float sx[S_], sy[S_], sz[S_];
    __shared__ float md[64][4][3];
    __shared__ int   mi[64][4][3];

    int b = blockIdx.x >> 7;
    int ntile = blockIdx.x & 127;
    const float* src = xyz2 + (size_t)b * S_ * 3;
    for (int i = threadIdx.x; i < S_; i += 256) {
        sx[i] = src[i * 3 + 0];
        sy[i] = src[i * 3 + 1];
        sz[i] = src[i * 3 + 2];
    }
    __syncthreads();

    int q  = threadIdx.x >> 2;
    int sp = threadIdx.x & 3;
    int n = ntile * 64 + q;
    size_t row = (size_t)b * N_ + n;
    float px = xyz1[row * 3 + 0], py = xyz1[row * 3 + 1], pz = xyz1[row * 3 + 2];

    float d0 = 1e30f, d1 = 1e30f, d2 = 1e30f;
    int i0 = 0, i1 = 0, i2 = 0;
    int sbeg = sp * (S_ / 4);
    #pragma unroll 8
    for (int s = sbeg; s < sbeg + S_ / 4; ++s) {
        float dx = px - sx[s], dy = py - sy[s], dz = pz - sz[s];
        float d = dx * dx + dy * dy + dz * dz;
        if (d < d2) {
            if (d < d1) {
                d2 = d1; i2 = i1;
                if (d < d0) { d1 = d0; i1 = i0; d0 = d; i0 = s; }
                else        { d1 = d;  i1 = s; }
            } else { d2 = d; i2 = s; }
        }
    }
    md[q][sp][0] = d0; md[q][sp][1] = d1; md[q][sp][2] = d2;
    mi[q][sp][0] = i0; mi[q][sp][1] = i1; mi[q][sp][2] = i2;
    __syncthreads();

    if (sp == 0) {
        #pragma unroll
        for (int p = 1; p < 4; ++p) {
            #pragma unroll
            for (int j = 0; j < 3; ++j) {
                float d = md[q][p][j]; int s = mi[q][p][j];
                if (d < d2) {
                    if (d < d1) {
                        d2 = d1; i2 = i1;
                        if (d < d0) { d1 = d0; i1 = i0; d0 = d; i0 = s; }
                        else        { d1 = d;  i1 = s; }
                    } else { d2 = d; i2 = s; }
                }
            }
        }
        float r0 = 1.f / (d0 + 1e-8f), r1 = 1.f / (d1 + 1e-8f), r2 = 1.f / (d2 + 1e-8f);
        float inv = 1.f / (r0 + r1 + r2);
        out_idx[row * 3 + 0] = i0; out_idx[row * 3 + 1] = i1; out_idx[row * 3 + 2] = i2;
        out_w[row * 3 + 0] = r0 * inv; out_w[row * 3 + 1] = r1 * inv; out_w[row * 3 + 2] = r2 * inv;
    }
}

// ---------------- gather + interp -> Abf cols [128,384) as bf16 ----------------
__global__ __launch_bounds__(256) void interp_kernel(
    const float* __restrict__ points2, const int* __restrict__ idx3,
    const float* __restrict__ w3, bf16* __restrict__ Abf)
{
    int t = threadIdx.x;
    size_t row = (size_t)blockIdx.x * 4 + (t >> 6);
    int lane = t & 63;
    int b = (int)(row >> 13);
    const float* p2 = points2 + (size_t)b * S_ * C2_;
    int ia = idx3[row * 3 + 0], ib = idx3[row * 3 + 1], ic = idx3[row * 3 + 2];
    float wa = w3[row * 3 + 0], wb = w3[row * 3 + 1], wc = w3[row * 3 + 2];
    float4 va = *(const float4*)(p2 + (size_t)ia * C2_ + lane * 4);
    float4 vb = *(const float4*)(p2 + (size_t)ib * C2_ + lane * 4);
    float4 vc = *(const float4*)(p2 + (size_t)ic * C2_ + lane * 4);
    bf16x4 o = { (bf16)(wa * va.x + wb * vb.x + wc * vc.x),
                 (bf16)(wa * va.y + wb * vb.y + wc * vc.y),
                 (bf16)(wa * va.z + wb * vb.z + wc * vc.z),
                 (bf16)(wa * va.w + wb * vb.w + wc * vc.w) };
    *(bf16x4*)(Abf + row * KA_ + C1_ + lane * 4) = o;
}

// ---------------- MFMA bf16 GEMM: C[r][o] = sum_k A[r][k] * Wt[o][k] ----------------
// 128x128 tile, BK=32, 4 waves (2x2, each 64x64). global_load_lds staging with
// source-side k-slot swizzle (slot = g ^ ((row>>1)&3)); linear LDS; swizzled ds_read.
// No bias: BN's batch-mean subtraction cancels it exactly.
template<int K, int OT, bool OUTBF>
__global__ __launch_bounds__(256) void mfma_gemm_kernel(
    const bf16* __restrict__ A, const bf16* __restrict__ Wt, void* __restrict__ Cout)
{
    __shared__ bf16 As[128 * 32];
    __shared__ bf16 Bs[128 * 32];
    const int tid = threadIdx.x;
    const int lane = tid & 63, wave = tid >> 6;
    const int wr = wave >> 1, wc = wave & 1;
    const int r0 = blockIdx.x * 128, o0 = blockIdx.y * 128;

    f32x4 acc[4][4] = {};

    const int l15 = lane & 15, g = lane >> 4;
    const int slot = g ^ ((l15 >> 1) & 3);          // k-slot swizzle (read side)
    int a_off[4], b_off[4];
    #pragma unroll
    for (int m = 0; m < 4; ++m) a_off[m] = (wr * 64 + m * 16 + l15) * 32 + slot * 8;
    #pragma unroll
    for (int n = 0; n < 4; ++n) b_off[n] = (wc * 64 + n * 16 + l15) * 32 + slot * 8;

    // staging descriptors: chunk c -> (row=c>>2, s=c&3) holds global kb = s ^ ((row>>1)&3)
    const int c0 = tid, c1 = tid + 256;
    const int ar0 = c0 >> 2, ar1 = c1 >> 2;
    const int kb0 = ((c0 & 3) ^ ((ar0 >> 1) & 3)) * 8;
    const int kb1 = ((c1 & 3) ^ ((ar1 >> 1) & 3)) * 8;

    for (int k0 = 0; k0 < K; k0 += 32) {
        __syncthreads();                     // previous tile's ds_reads done
        gload_lds16(A  + (size_t)(r0 + ar0) * K + k0 + kb0, &As[c0 * 8]);
        gload_lds16(A  + (size_t)(r0 + ar1) * K + k0 + kb1, &As[c1 * 8]);
        gload_lds16(Wt + (size_t)(o0 + ar0) * K + k0 + kb0, &Bs[c0 * 8]);
        gload_lds16(Wt + (size_t)(o0 + ar1) * K + k0 + kb1, &Bs[c1 * 8]);
        __syncthreads();                     // drains vmcnt(0) + barrier
        bf16x8 af[4], bfr[4];
        #pragma unroll
        for (int m = 0; m < 4; ++m) af[m]  = *(const bf16x8*)&As[a_off[m]];
        #pragma unroll
        for (int n = 0; n < 4; ++n) bfr[n] = *(const bf16x8*)&Bs[b_off[n]];
        #pragma unroll
        for (int m = 0; m < 4; ++m)
            #pragma unroll
            for (int n = 0; n < 4; ++n)
                acc[m][n] = __builtin_amdgcn_mfma_f32_16x16x32_bf16(af[m], bfr[n], acc[m][n], 0, 0, 0);
    }

    // C/D layout: col = lane&15, row = (lane>>4)*4 + reg  [m89/m91 verified]
    const int crow = r0 + wr * 64 + g * 4;
    const int ccol = o0 + wc * 64 + l15;
    #pragma unroll
    for (int m = 0; m < 4; ++m)
        #pragma unroll
        for (int n = 0; n < 4; ++n)
            #pragma unroll
            for (int j = 0; j < 4; ++j) {
                size_t off = (size_t)(crow + m * 16 + j) * OT + ccol + n * 16;
                if (OUTBF) ((bf16*)Cout)[off] = (bf16)acc[m][n][j];
                else       ((float*)Cout)[off] = acc[m][n][j];
            }
}

// ---------------- BN stats over bf16 [R][256] ----------------
__global__ __launch_bounds__(256) void stats_bf16_kernel(const bf16* __restrict__ X,
                                                         float* __restrict__ sums,
                                                         float* __restrict__ sumsq)
{
    __shared__ float ls[256], lq[256];
    int tid = threadIdx.x;
    ls[tid] = 0.f; lq[tid] = 0.f;
    __syncthreads();
    int cg = tid & 31, rs = tid >> 5;
    size_t r0 = (size_t)blockIdx.x * 512 + rs;
    float s[8] = {}, q[8] = {};
    for (int i = 0; i < 64; ++i) {
        bf16x8 v = *(const bf16x8*)(X + (r0 + (size_t)i * 8) * 256 + cg * 8);
        #pragma unroll
        for (int j = 0; j < 8; ++j) { float f = (float)v[j]; s[j] += f; q[j] += f * f; }
    }
    #pragma unroll
    for (int j = 0; j < 8; ++j) {
        atomicAdd(&ls[cg * 8 + j], s[j]);
        atomicAdd(&lq[cg * 8 + j], q[j]);
    }
    __syncthreads();
    atomicAdd(&sums[tid], ls[tid]);
    atomicAdd(&sumsq[tid], lq[tid]);
}

// ---------------- BN stats over f32 [R][128] ----------------
__global__ __launch_bounds__(256) void stats_f32_kernel(const float* __restrict__ X,
                                                        float* __restrict__ sums,
                                                        float* __restrict__ sumsq)
{
    __shared__ float ls[128], lq[128];
    int tid = threadIdx.x;
    if (tid < 128) { ls[tid] = 0.f; lq[tid] = 0.f; }
    __syncthreads();
    int cg = tid & 31, rs = tid >> 5;
    size_t r0 = (size_t)blockIdx.x * 512 + rs;
    float s[4] = {}, q[4] = {};
    for (int i = 0; i < 64; ++i) {
        float4 v = *(const float4*)(X + (r0 + (size_t)i * 8) * 128 + cg * 4);
        s[0] += v.x; q[0] += v.x * v.x;
        s[1] += v.y; q[1] += v.y * v.y;
        s[2] += v.z; q[2] += v.z * v.z;
        s[3] += v.w; q[3] += v.w * v.w;
    }
    #pragma unroll
    for (int j = 0; j < 4; ++j) {
        atomicAdd(&ls[cg * 4 + j], s[j]);
        atomicAdd(&lq[cg * 4 + j], q[j]);
    }
    __syncthreads();
    if (tid < 128) {
        atomicAdd(&sums[tid], ls[tid]);
        atomicAdd(&sumsq[tid], lq[tid]);
    }
}

__global__ void finalize_kernel(const float* __restrict__ sums, const float* __restrict__ sumsq,
                                const float* __restrict__ g, const float* __restrict__ be,
                                float* __restrict__ scale, float* __restrict__ shift, float invR)
{
    int c = threadIdx.x;
    float mean = sums[c] * invR;
    float var = sumsq[c] * invR - mean * mean;
    float s = g[c] * rsqrtf(var + 1e-5f);
    scale[c] = s;
    shift[c] = be[c] - mean * s;
}

// ---------------- BN+ReLU on bf16 h -> bf16 (feeds GEMM2) ----------------
__global__ __launch_bounds__(256) void bnrelu_cvt_kernel(const bf16* __restrict__ hp,
                                                         const float* __restrict__ scale,
                                                         const float* __restrict__ shift,
                                                         bf16* __restrict__ hb)
{
    size_t i8 = (size_t)blockIdx.x * 256 + threadIdx.x;
    int c0 = (int)((i8 * 8) & (H0_ - 1));
    bf16x8 v = *(const bf16x8*)(hp + i8 * 8);
    bf16x8 o;
    #pragma unroll
    for (int j = 0; j < 8; ++j) {
        float f = (float)v[j];
        f = fmaxf(0.f, f * scale[c0 + j] + shift[c0 + j]);
        o[j] = (bf16)f;
    }
    *(bf16x8*)(hb + i8 * 8) = o;
}

// ---------------- final in-place BN+ReLU on d_out (f32) ----------------
__global__ __launch_bounds__(256) void bnrelu_kernel(float* __restrict__ X,
                                                     const float* __restrict__ scale,
                                                     const float* __restrict__ shift)
{
    size_t i = (size_t)blockIdx.x * 256 + threadIdx.x;
    float4 v = *(float4*)(X + i * 4);
    int c = (int)((i * 4) & (H1_ - 1));
    v.x = fmaxf(0.f, v.x * scale[c + 0] + shift[c + 0]);
    v.y = fmaxf(0.f, v.y * scale[c + 1] + shift[c + 1]);
    v.z = fmaxf(0.f, v.z * scale[c + 2] + shift[c + 2]);
    v.w = fmaxf(0.f, v.w * scale[c + 3] + shift[c + 3]);
    *(float4*)(X + i * 4) = v;
}

extern "C" void kernel_launch(void* const* d_in, const int* in_sizes, int n_in,
                              void* d_out, int out_size, void* d_ws, size_t ws_size,
                              hipStream_t stream)
{
    const float* xyz1    = (const float*)d_in[0];
    const float* xyz2    = (const float*)d_in[1];
    const float* points1 = (const float*)d_in[2];
    const float* points2 = (const float*)d_in[3];
    const float* w0  = (const float*)d_in[4];
    const float* g0  = (const float*)d_in[6];
    const float* be0 = (const float*)d_in[7];
    const float* w1  = (const float*)d_in[8];
    const float* g1  = (const float*)d_in[10];
    const float* be1 = (const float*)d_in[11];
    float* out = (float*)d_out;
    char* ws = (char*)d_ws;

    bf16* Abf     = (bf16*)(ws);                    // 65536*384*2 = 50,331,648
    bf16* hpre_bf = (bf16*)(ws + 50331648);         // 65536*256*2 = 33,554,432
    bf16* hbf     = (bf16*)(ws + 83886080);         // 65536*256*2 = 33,554,432
    bf16* Wbf0    = (bf16*)(ws + 117440512);        // 256*384*2   =    196,608
    bf16* Wbf1    = (bf16*)(ws + 117637120);        // 128*256*2   =     65,536
    int*  idx3    = (int*) (ws + 117702656);        // 65536*3*4   =    786,432
    float* w3     = (float*)(ws + 118489088);       // 65536*3*4   =    786,432
    float* stats  = (float*)(ws + 119275520);       // 1536*4
    float* sums0 = stats,        *sumsq0 = stats + 256;
    float* sums1 = stats + 512,  *sumsq1 = stats + 640;
    float* scale0 = stats + 768,  *shift0 = stats + 1024;
    float* scale1 = stats + 1280, *shift1 = stats + 1408;

    zero_kernel<<<3, 256, 0, stream>>>(stats, 768);
    cvt_kernel<<<96, 256, 0, stream>>>(w0, Wbf0, H0_ * KA_ / 4);
    cvt_kernel<<<32, 256, 0, stream>>>(w1, Wbf1, H1_ * H0_ / 4);
    p1cvt_kernel<<<R_ * (C1_ / 4) / 256, 256, 0, stream>>>(points1, Abf);
    top3_kernel<<<B_ * (N_ / 64), 256, 0, stream>>>(xyz1, xyz2, idx3, w3);
    interp_kernel<<<R_ / 4, 256, 0, stream>>>(points2, idx3, w3, Abf);

    mfma_gemm_kernel<KA_, H0_, true><<<dim3(R_ / 128, 2), 256, 0, stream>>>(Abf, Wbf0, hpre_bf);
    stats_bf16_kernel<<<128, 256, 0, stream>>>(hpre_bf, sums0, sumsq0);
    finalize_kernel<<<1, 256, 0, stream>>>(sums0, sumsq0, g0, be0, scale0, shift0, 1.f / R_);
    bnrelu_cvt_kernel<<<R_ * H0_ / 8 / 256, 256, 0, stream>>>(hpre_bf, scale0, shift0, hbf);

    mfma_gemm_kernel<H0_, H1_, false><<<dim3(R_ / 128, 1), 256, 0, stream>>>(hbf, Wbf1, out);
    stats_f32_kernel<<<128, 256, 0, stream>>>(out, sums1, sumsq1);
    finalize_kernel<<<1, 128, 0, stream>>>(sums1, sumsq1, g1, be1, scale1, shift1, 1.f / R_);
    bnrelu_kernel<<<R_ * H1_ / 4 / 256, 256, 0, stream>>>(out, scale1, shift1);
}